// Round 4
// baseline (513.788 us; speedup 1.0000x reference)
//
#include <hip/hip_runtime.h>

// CRF Viterbi forward decode — R7 (resubmit; prior round hit GPU-acquisition
// timeout, never measured): 4-wave source-split for TLP.
// potentials: [1024, 512, 48] f32, transition: [48, 48] f32.
// out = backpointers [1024, 511, 48] (float-encoded) ++ scores [1024, 48] f32.
//
// R6 post-mortem: dispatch = 205 us, 965 cyc/step, VALUBusy 70%, occupancy
// 1 wave/SIMD (1024 waves on 1024 SIMDs). Dependency stalls (~290 cyc/step:
// LDS round trip + serial 47-deep eq-scan chain) have nothing to hide under.
// Wave count is pinned by the decomposition, not by resources.
//
// R7: split the 48 SOURCE tags across 4 waves per batch (12 each).
//  - 4096 waves -> 4 waves/SIMD: stalls of one block hide under others.
//  - Per-wave per-step issue ~675 -> ~180 cyc: 12 adds, 12-max ternary tree,
//    12-wide PARALLEL first-occurrence argmax (eq-encode + fmin tree) instead
//    of the 47-deep serial cndmask scan.
//  - State broadcast via v_readlane (wave w's 12 source states live in its
//    OWN lanes 12w..12w+11): the per-step LDS state round trip is gone.
//  - Cross-wave combine: each wave writes float2{pm, argmaxf} to LDS,
//    one __syncthreads, all waves read 4 partials and combine with a
//    left-priority max tree (exact first-occurrence tie-break).
//  - Partial buffer parity-double-buffered: write(t+1) races read(t) inside
//    one barrier interval; parity is a compile-time literal per slot.
//  - Rotating bp store-data regs (R6) kept: store source reg redefined only
//    6 steps later, no per-step vmcnt store-ack stall.
// Lanes 48..63: j clamped to 47 (compute duplicates lane 47, stores masked,
// never readlane'd) so all lanes reach every barrier uniformly.

constexpr int B_ = 1024;
constexpr int T_ = 512;
constexpr int K_ = 48;
constexpr int C_ = 6;     // steps t=2..511 -> 510 = 6 * 85, no remainder
constexpr int NW_ = 4;    // waves per block (source split)
constexpr int IS_ = 12;   // sources per wave

__global__ __launch_bounds__(256, 4) void crf_viterbi_kernel(
    const float* __restrict__ pot,
    const float* __restrict__ trans,
    float* __restrict__ out)
{
    const int b    = blockIdx.x;
    const int tid  = threadIdx.x;
    const int w    = tid >> 6;        // wave id 0..3
    const int lane = tid & 63;
    const int j    = (lane < K_) ? lane : (K_ - 1);  // clamped destination tag
    const bool st_ok = (lane < K_);
    const int IB   = w * IS_;         // this wave's source base

    // Parity-double-buffered cross-wave partials: {partial max, argmax as float}.
    __shared__ float2 part[2][NW_][K_];

    // Transition rows IB..IB+11, column j -> 12 VGPRs.
    float tcol[IS_];
    #pragma unroll
    for (int k = 0; k < IS_; ++k) tcol[k] = trans[(IB + k) * K_ + j];

    // Global source indices as floats (exact small ints) + sentinel.
    float idxf[IS_];
    #pragma unroll
    for (int k = 0; k < IS_; ++k) idxf[k] = (float)(IB + k);
    const float BIGF = 256.0f;

    const float* pp = pot + (size_t)b * T_ * K_ + j;
    float* bpp      = out + (size_t)b * (T_ - 1) * K_ + j;   // walking bp ptr
    float* scout    = out + (size_t)B_ * (T_ - 1) * K_ + (size_t)b * K_ + j;

    // t = 0 state; broadcast this wave's 12 source states via readlane.
    float myst = pp[0];
    float st[IS_];
    #pragma unroll
    for (int k = 0; k < IS_; ++k)
        st[k] = __int_as_float(
            __builtin_amdgcn_readlane(__float_as_int(myst), IB + k));

    // Rotating bp store-data registers (redefined 6 steps after their store).
    float bpf0 = 0.0f, bpf1 = 0.0f, bpf2 = 0.0f,
          bpf3 = 0.0f, bpf4 = 0.0f, bpf5 = 0.0f;

// One step t: cand over this wave's 12 sources, partial max + parallel
// first-occurrence argmax, LDS combine, bp row (t-1) store, state update.
// PAR is a compile-time parity literal; BPV a rotating store register.
#define STEP(PCUR, PAR, BPV)                                                   \
    do {                                                                       \
        float cand[IS_];                                                       \
        _Pragma("unroll")                                                      \
        for (int k = 0; k < IS_; ++k) cand[k] = st[k] + tcol[k];               \
        /* partial max: ternary tree, depth 2 (v_max3) */                      \
        float a0 = fmaxf(fmaxf(cand[0], cand[1]),  cand[2]);                   \
        float a1 = fmaxf(fmaxf(cand[3], cand[4]),  cand[5]);                   \
        float a2 = fmaxf(fmaxf(cand[6], cand[7]),  cand[8]);                   \
        float a3 = fmaxf(fmaxf(cand[9], cand[10]), cand[11]);                  \
        float pm = fmaxf(fmaxf(a0, a1), fmaxf(a2, a3));                        \
        /* parallel first-occurrence argmax: eq-encode + fmin tree */          \
        float e0  = (cand[0]  == pm) ? idxf[0]  : BIGF;                        \
        float e1  = (cand[1]  == pm) ? idxf[1]  : BIGF;                        \
        float e2  = (cand[2]  == pm) ? idxf[2]  : BIGF;                        \
        float e3  = (cand[3]  == pm) ? idxf[3]  : BIGF;                        \
        float e4  = (cand[4]  == pm) ? idxf[4]  : BIGF;                        \
        float e5  = (cand[5]  == pm) ? idxf[5]  : BIGF;                        \
        float e6  = (cand[6]  == pm) ? idxf[6]  : BIGF;                        \
        float e7  = (cand[7]  == pm) ? idxf[7]  : BIGF;                        \
        float e8  = (cand[8]  == pm) ? idxf[8]  : BIGF;                        \
        float e9  = (cand[9]  == pm) ? idxf[9]  : BIGF;                        \
        float e10 = (cand[10] == pm) ? idxf[10] : BIGF;                        \
        float e11 = (cand[11] == pm) ? idxf[11] : BIGF;                        \
        float f0 = fminf(fminf(e0, e1),  e2);                                  \
        float f1 = fminf(fminf(e3, e4),  e5);                                  \
        float f2 = fminf(fminf(e6, e7),  e8);                                  \
        float f3 = fminf(fminf(e9, e10), e11);                                 \
        float af = fminf(fminf(f0, f1), fminf(f2, f3));                        \
        part[PAR][w][j] = make_float2(pm, af);                                 \
        __syncthreads();                                                       \
        float2 q0 = part[PAR][0][j];                                           \
        float2 q1 = part[PAR][1][j];                                           \
        float2 q2 = part[PAR][2][j];                                           \
        float2 q3 = part[PAR][3][j];                                           \
        /* left-priority combine tree: earlier wave wins ties (first-occ). */  \
        bool c01 = (q1.x > q0.x);                                              \
        float bm01 = c01 ? q1.x : q0.x;                                        \
        float bp01 = c01 ? q1.y : q0.y;                                        \
        bool c23 = (q3.x > q2.x);                                              \
        float bm23 = c23 ? q3.x : q2.x;                                        \
        float bp23 = c23 ? q3.y : q2.y;                                        \
        bool cw = (bm23 > bm01);                                               \
        float bm = cw ? bm23 : bm01;                                           \
        BPV = cw ? bp23 : bp01;                                                \
        if (w == 0 && st_ok) *bpp = BPV;   /* bp row t-1 */                    \
        bpp += K_;                                                             \
        myst = (PCUR) + bm;                                                    \
        _Pragma("unroll")                                                      \
        for (int k = 0; k < IS_; ++k)                                          \
            st[k] = __int_as_float(                                            \
                __builtin_amdgcn_readlane(__float_as_int(myst), IB + k));      \
    } while (0)

    // Potential for t=1 and prefetch t=2..7.
    float p1 = pp[(size_t)1 * K_];
    float pbuf[C_];
    #pragma unroll
    for (int u = 0; u < C_; ++u) pbuf[u] = pp[(size_t)(2 + u) * K_];

    // t = 1 (parity 1).
    STEP(p1, 1, bpf5);

    for (int t0 = 2; t0 < T_; t0 += C_) {   // t0 = 2, 8, ..., 506 (85 chunks)
        float pc[C_];
        #pragma unroll
        for (int u = 0; u < C_; ++u) pc[u] = pbuf[u];

        // Prefetch next chunk (clamped; dup loads harmless; 6-step slack).
        #pragma unroll
        for (int u = 0; u < C_; ++u) {
            int tn = t0 + C_ + u;
            if (tn > T_ - 1) tn = T_ - 1;
            pbuf[u] = pp[(size_t)tn * K_];
        }

        // t = t0 + u; t0 is even, so parity = u & 1 (compile-time per slot).
        STEP(pc[0], 0, bpf0);
        STEP(pc[1], 1, bpf1);
        STEP(pc[2], 0, bpf2);
        STEP(pc[3], 1, bpf3);
        STEP(pc[4], 0, bpf4);
        STEP(pc[5], 1, bpf5);
    }

    // Keep rotating store regs live (defeat DSE of the rotation).
    asm volatile("" :: "v"(bpf0), "v"(bpf1), "v"(bpf2),
                       "v"(bpf3), "v"(bpf4), "v"(bpf5));

    // Final Viterbi scores (S(511)), wave 0 only.
    if (w == 0 && st_ok) *scout = myst;
#undef STEP
}

extern "C" void kernel_launch(void* const* d_in, const int* in_sizes, int n_in,
                              void* d_out, int out_size, void* d_ws, size_t ws_size,
                              hipStream_t stream) {
    const float* pot   = (const float*)d_in[0];
    const float* trans = (const float*)d_in[1];
    float* out         = (float*)d_out;
    crf_viterbi_kernel<<<dim3(B_), dim3(256), 0, stream>>>(pot, trans, out);
}

// Round 6
// 322.715 us; speedup vs baseline: 1.5921x; 1.5921x over previous
//
#include <hip/hip_runtime.h>

// CRF Viterbi forward decode — R8 (resubmit; prior round hit GPU-acquisition
// timeout, never measured): R6 skeleton + in-step inline-const argmax.
// potentials: [1024, 512, 48] f32, transition: [48, 48] f32.
// out = backpointers [1024, 511, 48] (float-encoded) ++ scores [1024, 48] f32.
//
// R7 post-mortem (414 us, REGRESSED): 4-wave split kept total issue per
// (batch,step) constant (~340 insts) while adding barrier/combine/readlane
// overhead; VGPR=40 shows launch_bounds(256,4) starved the allocator into
// spilling (~190 insts/wave/step measured vs 85 modeled); and __syncthreads
// drains vmcnt(0), serializing bp store-ack + pbuf prefetch into the chain.
//
// R8 attacks instruction count instead. R6's serial 47-deep eq-scan cost
// ~141 insts/step (47 cmp + 47 cndmask + ~47 v_mov literal materializations)
// and forced candA/B double-buffering. Replacement:
//   e[i] = (cand[i]==mm) ? i : 63      // v_cmp + v_cndmask, BOTH inline
//                                      // consts (i<=47, 63 <= 64) — no movs
//   xx   = min3-tree(e)                // 24 v_min3_i32, depth 4
// ~121 insts, fully parallel, placed AFTER the ds_write+wave_barrier so the
// next step's 12 ds_read_b128 issue first and their latency hides under it.
// Exactness: mm comes from the same max3 tree as R6 (bit-identical values);
// min-of-equal-indices == first-occurrence argmax; -0/+0 ties are handled
// by == (equal). Double buffer gone (-48 live VGPRs); bp row t-1 written
// in step t, no trailing fixup.
//
// Block = 1 wave, 48 lanes, lane j = destination tag; 1 block per batch.
// wave_barrier = scheduling fence only (single-wave workgroup, in-order DS
// pipe — validated R2/R3, absmax 0 through R7). No vmcnt drains anywhere.

constexpr int B_ = 1024;
constexpr int T_ = 512;
constexpr int K_ = 48;
constexpr int C_ = 6;   // steps t=2..511 -> 510 = 6 * 85, no remainder

__device__ __forceinline__ int min3i(int a, int b, int c) {
    int m = a < b ? a : b;
    return m < c ? m : c;   // -> v_min3_i32
}

__global__ __launch_bounds__(64, 1) void crf_viterbi_kernel(
    const float* __restrict__ pot,
    const float* __restrict__ trans,
    float* __restrict__ out)
{
    const int b = blockIdx.x;
    const int j = threadIdx.x;  // 0..47 = destination tag

    __shared__ __align__(16) float stv[K_];  // wave-synchronous state buffer

    // Transition column j -> 48 VGPRs (reused 511 times).
    float tcol[K_];
    #pragma unroll
    for (int i = 0; i < K_; ++i) tcol[i] = trans[i * K_ + j];

    const float* pp = pot + (size_t)b * T_ * K_ + j;
    float* bpp      = out + (size_t)b * (T_ - 1) * K_ + j;   // walking bp ptr
    float* scout    = out + (size_t)B_ * (T_ - 1) * K_ + (size_t)b * K_ + j;

    // t = 0 state.
    float myst = pp[0];
    stv[j] = myst;
    __builtin_amdgcn_wave_barrier();

    // Rotating bp store-data registers: slot u redefined only 6 steps after
    // its store -> no per-step vmcnt store-ack WAR stall (R6 insurance).
    float bpf0 = 0.0f, bpf1 = 0.0f, bpf2 = 0.0f,
          bpf3 = 0.0f, bpf4 = 0.0f, bpf5 = 0.0f;

// One step t (t = 1..511): read S(t-1), cand, max -> S(t) -> LDS; then the
// in-step argmax + bp row (t-1) store runs AFTER the barrier so next step's
// ds_reads can interleave with it.
#define STEP(PCUR, BPV)                                                        \
    do {                                                                       \
        /* (1) Batched broadcast reads — 12 x ds_read_b128, static offsets. */ \
        float4 sv[12];                                                         \
        const float4* stv4 = (const float4*)stv;                               \
        _Pragma("unroll")                                                      \
        for (int c = 0; c < 12; ++c) sv[c] = stv4[c];                          \
        /* (2) 48 candidates (transient — consumed this step). */              \
        float cand[K_];                                                        \
        _Pragma("unroll")                                                      \
        for (int c = 0; c < 12; ++c) {                                         \
            cand[4 * c + 0] = sv[c].x + tcol[4 * c + 0];                       \
            cand[4 * c + 1] = sv[c].y + tcol[4 * c + 1];                       \
            cand[4 * c + 2] = sv[c].z + tcol[4 * c + 2];                       \
            cand[4 * c + 3] = sv[c].w + tcol[4 * c + 3];                       \
        }                                                                      \
        /* (3) Ternary value tree -> v_max3_f32: 16+5+2+1 = 24 ops, depth 4.*/ \
        float m1[16];                                                          \
        _Pragma("unroll")                                                      \
        for (int k = 0; k < 16; ++k)                                           \
            m1[k] = fmaxf(fmaxf(cand[3 * k], cand[3 * k + 1]), cand[3 * k + 2]); \
        float m2[6];                                                           \
        _Pragma("unroll")                                                      \
        for (int k = 0; k < 5; ++k)                                            \
            m2[k] = fmaxf(fmaxf(m1[3 * k], m1[3 * k + 1]), m1[3 * k + 2]);     \
        m2[5] = m1[15];                                                        \
        float mm = fmaxf(fmaxf(fmaxf(m2[0], m2[1]), m2[2]),                    \
                         fmaxf(fmaxf(m2[3], m2[4]), m2[5]));                   \
        /* (4) New state -> LDS; fence orders write(t) before reads(t+1). */   \
        myst = (PCUR) + mm;                                                    \
        stv[j] = myst;                                                         \
        __builtin_amdgcn_wave_barrier();                                       \
        /* (5) In-step parallel first-occurrence argmax, inline consts only:   \
           e[i] = eq ? i : 63 (i, 63 are VOP3 inline constants — no v_mov),    \
           then v_min3_i32 tree. Runs under next step's ds_read latency. */    \
        int e[K_];                                                             \
        _Pragma("unroll")                                                      \
        for (int i = 0; i < K_; ++i) e[i] = (cand[i] == mm) ? i : 63;          \
        int n1[16];                                                            \
        _Pragma("unroll")                                                      \
        for (int k = 0; k < 16; ++k)                                           \
            n1[k] = min3i(e[3 * k], e[3 * k + 1], e[3 * k + 2]);               \
        int n2[6];                                                             \
        _Pragma("unroll")                                                      \
        for (int k = 0; k < 5; ++k)                                            \
            n2[k] = min3i(n1[3 * k], n1[3 * k + 1], n1[3 * k + 2]);            \
        n2[5] = n1[15];                                                        \
        int n30 = min3i(n2[0], n2[1], n2[2]);                                  \
        int n31 = min3i(n2[3], n2[4], n2[5]);                                  \
        int xx = n30 < n31 ? n30 : n31;                                        \
        BPV = (float)xx;                                                       \
        *bpp = BPV;            /* bp row t-1 */                                \
        bpp += K_;                                                             \
    } while (0)

    // Potential for t=1 and prefetch t=2..7.
    float p1 = pp[(size_t)1 * K_];
    float pbuf[C_];
    #pragma unroll
    for (int u = 0; u < C_; ++u) pbuf[u] = pp[(size_t)(2 + u) * K_];

    // t = 1.
    STEP(p1, bpf5);

    for (int t0 = 2; t0 < T_; t0 += C_) {   // t0 = 2, 8, ..., 506 (85 chunks)
        float pc[C_];
        #pragma unroll
        for (int u = 0; u < C_; ++u) pc[u] = pbuf[u];

        // Prefetch next chunk (clamped; dup loads harmless; 6-step slack,
        // and no vmcnt-draining barriers anywhere to expose the latency).
        #pragma unroll
        for (int u = 0; u < C_; ++u) {
            int tn = t0 + C_ + u;
            if (tn > T_ - 1) tn = T_ - 1;
            pbuf[u] = pp[(size_t)tn * K_];
        }

        STEP(pc[0], bpf0);
        STEP(pc[1], bpf1);
        STEP(pc[2], bpf2);
        STEP(pc[3], bpf3);
        STEP(pc[4], bpf4);
        STEP(pc[5], bpf5);
    }

    // Keep rotating store regs live (defeat DSE of the rotation).
    asm volatile("" :: "v"(bpf0), "v"(bpf1), "v"(bpf2),
                       "v"(bpf3), "v"(bpf4), "v"(bpf5));

    // Final Viterbi scores (S(511)).
    *scout = myst;
#undef STEP
}

extern "C" void kernel_launch(void* const* d_in, const int* in_sizes, int n_in,
                              void* d_out, int out_size, void* d_ws, size_t ws_size,
                              hipStream_t stream) {
    const float* pot   = (const float*)d_in[0];
    const float* trans = (const float*)d_in[1];
    float* out         = (float*)d_out;
    crf_viterbi_kernel<<<dim3(B_), dim3(K_), 0, stream>>>(pot, trans, out);
}